// Round 2
// baseline (3740.302 us; speedup 1.0000x reference)
//
#include <hip/hip_runtime.h>
#include <hip/hip_cooperative_groups.h>

namespace cg = cooperative_groups;

// Sizes
#define T 70
#define B 64
#define E 512
#define H 512
#define V 10000
#define TB (T*B)            // 4480
#define SLOT (H*B)          // 32768 floats per (t) state slot
#define LOGITS_N (T*B*V)    // 44800000

typedef __bf16 bf16x8 __attribute__((ext_vector_type(8)));
typedef __bf16 bf16x4 __attribute__((ext_vector_type(4)));
typedef float  f32x4  __attribute__((ext_vector_type(4)));

__device__ __forceinline__ float ftanh(float x) {
    float e = __expf(2.0f * x);
    return 1.0f - 2.0f / (e + 1.0f);
}

// ---------------------------------------------------------------------------
// 1) Embedding gather: X[t][b][e] (row-major) = emb_table[ids[t][b]][e]
// ---------------------------------------------------------------------------
__global__ __launch_bounds__(256) void gather_emb(const int* __restrict__ ids,
                                                  const float* __restrict__ emb,
                                                  float* __restrict__ X) {
    int i = blockIdx.x * 256 + threadIdx.x;
    if (i >= TB * (E / 4)) return;
    int tok = i >> 7;
    int e4 = i & 127;
    int id = ids[tok];
    ((float4*)X)[i] = ((const float4*)emb)[id * 128 + e4];
}

// ---------------------------------------------------------------------------
// 2) Transpose initial hidden (L,B,H) row-major -> k4-packed slots
// ---------------------------------------------------------------------------
__global__ __launch_bounds__(256) void hinit_k(const float* __restrict__ hidden,
                                               float* __restrict__ H0,
                                               float* __restrict__ H1) {
    int i = blockIdx.x * 256 + threadIdx.x;
    if (i >= 2 * SLOT) return;
    int l = i >> 15, r = i & (SLOT - 1);
    int k4 = r >> 8, q = r & 255, b = q >> 2, kk = q & 3;
    int h = k4 * 4 + kk;
    float v = hidden[l * SLOT + b * H + h];
    (l ? H1 : H0)[r] = v;
}

// ---------------------------------------------------------------------------
// 3) P0 = X @ W0x.T + b0   -> layout (T, N=512, B=64)  (fp32 VALU GEMM)
// ---------------------------------------------------------------------------
__global__ __launch_bounds__(256) void gemm_p0(const float* __restrict__ X,
                                               const float* __restrict__ W0,
                                               const float* __restrict__ b0v,
                                               float* __restrict__ P0) {
    __shared__ float As[32][68];
    __shared__ float Ws[32][68];
    int t = blockIdx.y;
    int n0 = blockIdx.x * 64;
    int tid = threadIdx.x;
    int bq = tid & 15;
    int nq = tid >> 4;
    const float* A = X + t * 64 * E;
    float acc[4][4] = {{0.f}};

    for (int kc = 0; kc < 512; kc += 32) {
        for (int i = tid; i < 512; i += 256) {
            int bb = i >> 3, kq = i & 7;
            float4 a = *(const float4*)(A + bb * E + kc + kq * 4);
            As[kq*4+0][bb] = a.x; As[kq*4+1][bb] = a.y;
            As[kq*4+2][bb] = a.z; As[kq*4+3][bb] = a.w;
        }
        for (int i = tid; i < 512; i += 256) {
            int nn = i >> 3, kq = i & 7;
            float4 w = *(const float4*)(W0 + (size_t)(n0 + nn) * 1024 + kc + kq * 4);
            Ws[kq*4+0][nn] = w.x; Ws[kq*4+1][nn] = w.y;
            Ws[kq*4+2][nn] = w.z; Ws[kq*4+3][nn] = w.w;
        }
        __syncthreads();
#pragma unroll
        for (int kk = 0; kk < 32; kk++) {
            float4 a = *(const float4*)&As[kk][bq * 4];
            float4 w = *(const float4*)&Ws[kk][nq * 4];
            acc[0][0] += a.x*w.x; acc[0][1] += a.x*w.y; acc[0][2] += a.x*w.z; acc[0][3] += a.x*w.w;
            acc[1][0] += a.y*w.x; acc[1][1] += a.y*w.y; acc[1][2] += a.y*w.z; acc[1][3] += a.y*w.w;
            acc[2][0] += a.z*w.x; acc[2][1] += a.z*w.y; acc[2][2] += a.z*w.z; acc[2][3] += a.z*w.w;
            acc[3][0] += a.w*w.x; acc[3][1] += a.w*w.y; acc[3][2] += a.w*w.z; acc[3][3] += a.w*w.w;
        }
        __syncthreads();
    }
#pragma unroll
    for (int j = 0; j < 4; j++) {
        int n = n0 + nq * 4 + j;
        float bias = b0v[n];
        float4 r = make_float4(acc[0][j] + bias, acc[1][j] + bias,
                               acc[2][j] + bias, acc[3][j] + bias);
        *(float4*)(P0 + (size_t)t * SLOT + n * 64 + bq * 4) = r;
    }
}

// ---------------------------------------------------------------------------
// 4) Cooperative pipelined chain: one launch, grid.sync() between steps.
//    blocks 0..63  : layer0, 8 rows each (2 rows/wave)
//    blocks 64..127: layer1, 8 rows each (2 rows/wave)
//    Slots k4-packed: addr = k4*256 + b*4 + (k&3); slot s = h at t=s-1.
// ---------------------------------------------------------------------------
__global__ __launch_bounds__(256) void chain_coop(const float* __restrict__ P0,
                                                  float* __restrict__ H0,
                                                  float* __restrict__ H1,
                                                  const float* __restrict__ W0,
                                                  const float* __restrict__ W1,
                                                  const float* __restrict__ b1v) {
    cg::grid_group grid = cg::this_grid();
    int tid = threadIdx.x;
    int b = tid & 63;
    int wv = tid >> 6;
    int bid = blockIdx.x;
    bool is0 = bid < 64;
    int n0 = (is0 ? bid : (bid - 64)) * 8 + wv * 2;

    for (int s = 0; s <= T; s++) {
        if (is0) {
            if (s < T) {
                const float4* A = (const float4*)(H0 + (size_t)s * SLOT);  // h0[s-1]
                const float* w0 = W0 + (size_t)n0 * 1024 + 512;
                const float* w1 = W0 + (size_t)(n0 + 1) * 1024 + 512;
                float acc0 = P0[(size_t)s * SLOT + n0 * 64 + b];
                float acc1 = P0[(size_t)s * SLOT + (n0 + 1) * 64 + b];
#pragma unroll 4
                for (int k4 = 0; k4 < 128; k4++) {
                    float4 a = A[k4 * 64 + b];
                    int k = k4 * 4;
                    acc0 += a.x * w0[k] + a.y * w0[k+1] + a.z * w0[k+2] + a.w * w0[k+3];
                    acc1 += a.x * w1[k] + a.y * w1[k+1] + a.z * w1[k+2] + a.w * w1[k+3];
                }
                float o0 = ftanh(acc0), o1 = ftanh(acc1);
                float* dst = H0 + (size_t)(s + 1) * SLOT + (n0 >> 2) * 256 + b * 4 + (n0 & 3);
                dst[0] = o0; dst[1] = o1;
            }
        } else {
            if (s >= 1) {
                int t1 = s - 1;
                const float4* Aa = (const float4*)(H0 + (size_t)(t1 + 1) * SLOT); // h0[t1]
                const float4* Ab = (const float4*)(H1 + (size_t)t1 * SLOT);       // h1[t1-1]
                const float* wa0 = W1 + (size_t)n0 * 1024;
                const float* wa1 = W1 + (size_t)(n0 + 1) * 1024;
                const float* wb0 = wa0 + 512;
                const float* wb1 = wa1 + 512;
                float acc0 = b1v[n0], acc1 = b1v[n0 + 1];
#pragma unroll 4
                for (int k4 = 0; k4 < 128; k4++) {
                    float4 a = Aa[k4 * 64 + b];
                    float4 c = Ab[k4 * 64 + b];
                    int k = k4 * 4;
                    acc0 += a.x * wa0[k] + a.y * wa0[k+1] + a.z * wa0[k+2] + a.w * wa0[k+3];
                    acc1 += a.x * wa1[k] + a.y * wa1[k+1] + a.z * wa1[k+2] + a.w * wa1[k+3];
                    acc0 += c.x * wb0[k] + c.y * wb0[k+1] + c.z * wb0[k+2] + c.w * wb0[k+3];
                    acc1 += c.x * wb1[k] + c.y * wb1[k+1] + c.z * wb1[k+2] + c.w * wb1[k+3];
                }
                float o0 = ftanh(acc0), o1 = ftanh(acc1);
                float* dst = H1 + (size_t)(t1 + 1) * SLOT + (n0 >> 2) * 256 + b * 4 + (n0 & 3);
                dst[0] = o0; dst[1] = o1;
            }
        }
        grid.sync();
    }
}

// ---------------------------------------------------------------------------
// 5a) Wout fp32 -> bf16 (row-major, same layout)
// ---------------------------------------------------------------------------
__global__ __launch_bounds__(256) void wconv(const float* __restrict__ W,
                                             __bf16* __restrict__ Wb, int n4) {
    int i = blockIdx.x * 256 + threadIdx.x;
    if (i >= n4) return;
    float4 w = ((const float4*)W)[i];
    *(bf16x4*)(Wb + (size_t)i * 4) = (bf16x4){(__bf16)w.x, (__bf16)w.y, (__bf16)w.z, (__bf16)w.w};
}

// ---------------------------------------------------------------------------
// 5b) H1 slots (k4-packed fp32) -> A bf16 row-major (4480, 512)
// ---------------------------------------------------------------------------
__global__ __launch_bounds__(256) void aconv(const float* __restrict__ H1,
                                             __bf16* __restrict__ Abf) {
    int t = blockIdx.x;
    const float4* src = (const float4*)(H1 + (size_t)(t + 1) * SLOT);
    for (int i = threadIdx.x; i < 8192; i += 256) {
        int b = i >> 7, k4 = i & 127;
        float4 a = src[k4 * 64 + b];
        __bf16* dst = Abf + ((size_t)t * 64 + b) * 512 + k4 * 4;
        *(bf16x4*)dst = (bf16x4){(__bf16)a.x, (__bf16)a.y, (__bf16)a.z, (__bf16)a.w};
    }
}

// ---------------------------------------------------------------------------
// 6) logits = tanh(A @ Wout.T + bout) via bf16 MFMA, fp32 accumulate.
//    M-tile = 64 (one t-slot), N-tile = 128, BK = 64, xor-swizzled LDS.
// ---------------------------------------------------------------------------
__global__ __launch_bounds__(256) void logits_mfma(const __bf16* __restrict__ A,
                                                   const __bf16* __restrict__ Wb,
                                                   const float* __restrict__ boutv,
                                                   float* __restrict__ out) {
    __shared__ __bf16 As[64 * 64];
    __shared__ __bf16 Bs[128 * 64];
    int t = blockIdx.y;
    int v0 = blockIdx.x * 128;
    int tid = threadIdx.x;
    int lane = tid & 63;
    int w = tid >> 6;
    int l15 = lane & 15;
    int q = lane >> 4;

    f32x4 acc[4][2] = {};
    const __bf16* Ap = A + (size_t)t * 64 * 512;

    for (int kc = 0; kc < 512; kc += 64) {
#pragma unroll
        for (int it = 0; it < 2; it++) {
            int cl = tid + it * 256;
            int m = cl >> 3, c = cl & 7;
            bf16x8 v = *(const bf16x8*)(Ap + m * 512 + kc + c * 8);
            *(bf16x8*)(&As[m * 64 + ((c ^ (m & 7)) * 8)]) = v;
        }
#pragma unroll
        for (int it = 0; it < 4; it++) {
            int cl = tid + it * 256;
            int n = cl >> 3, c = cl & 7;
            int vv = v0 + n;
            bf16x8 val = {};
            if (vv < V) val = *(const bf16x8*)(Wb + (size_t)vv * 512 + kc + c * 8);
            *(bf16x8*)(&Bs[n * 64 + ((c ^ (n & 7)) * 8)]) = val;
        }
        __syncthreads();
#pragma unroll
        for (int s = 0; s < 2; s++) {
            int c = s * 4 + q;
            bf16x8 af[4], bfv[2];
#pragma unroll
            for (int mt = 0; mt < 4; mt++) {
                int m = mt * 16 + l15;
                af[mt] = *(const bf16x8*)(&As[m * 64 + ((c ^ (m & 7)) * 8)]);
            }
#pragma unroll
            for (int nt = 0; nt < 2; nt++) {
                int n = w * 32 + nt * 16 + l15;
                bfv[nt] = *(const bf16x8*)(&Bs[n * 64 + ((c ^ (n & 7)) * 8)]);
            }
#pragma unroll
            for (int mt = 0; mt < 4; mt++)
#pragma unroll
                for (int nt = 0; nt < 2; nt++)
                    acc[mt][nt] = __builtin_amdgcn_mfma_f32_16x16x32_bf16(af[mt], bfv[nt], acc[mt][nt], 0, 0, 0);
        }
        __syncthreads();
    }

#pragma unroll
    for (int nt = 0; nt < 2; nt++) {
        int col = v0 + w * 32 + nt * 16 + l15;
        if (col < V) {
            float bias = boutv[col];
#pragma unroll
            for (int mt = 0; mt < 4; mt++) {
#pragma unroll
                for (int r = 0; r < 4; r++) {
                    int row = mt * 16 + q * 4 + r;
                    out[((size_t)t * 64 + row) * V + col] = ftanh(acc[mt][nt][r] + bias);
                }
            }
        }
    }
}

// ---------------------------------------------------------------------------
// 7) Final hidden -> d_out tail, (L,B,H) row-major
// ---------------------------------------------------------------------------
__global__ __launch_bounds__(256) void hfinal_k(const float* __restrict__ H0,
                                                const float* __restrict__ H1,
                                                float* __restrict__ out) {
    int i = blockIdx.x * 256 + threadIdx.x;
    if (i >= 2 * SLOT) return;
    int l = i >> 15, r = i & (SLOT - 1);
    int b = r >> 9, h = r & 511;
    const float* Hp = l ? H1 : H0;
    out[LOGITS_N + i] = Hp[(size_t)T * SLOT + (h >> 2) * 256 + b * 4 + (h & 3)];
}

// ---------------------------------------------------------------------------
extern "C" void kernel_launch(void* const* d_in, const int* in_sizes, int n_in,
                              void* d_out, int out_size, void* d_ws, size_t ws_size,
                              hipStream_t stream) {
    const int*   ids    = (const int*)d_in[0];
    const float* hidden = (const float*)d_in[1];
    const float* emb    = (const float*)d_in[2];
    const float* W0     = (const float*)d_in[3];
    const float* b0v    = (const float*)d_in[4];
    const float* W1     = (const float*)d_in[5];
    const float* b1v    = (const float*)d_in[6];
    const float* Wout   = (const float*)d_in[7];
    const float* boutv  = (const float*)d_in[8];
    float* out = (float*)d_out;
    float* ws  = (float*)d_ws;

    // ws layout (floats): [H0: 2,326,528][H1: 2,326,528][P0: 2,293,760][X: 2,293,760]
    // After chain: Wbf16 aliases P0 (+ spills 266,240 floats into X's head);
    //              Abf16 aliases X at offset 266,240.  Total = 9,240,576 floats.
    float* H0 = ws;
    float* H1 = ws + 2326528;
    float* P0 = ws + 4653056;
    float* X  = ws + 6946816;
    __bf16* Wbf = (__bf16*)(ws + 4653056);            // 5,120,000 bf16
    __bf16* Abf = (__bf16*)(ws + 6946816 + 266240);   // 2,293,760 bf16

    gather_emb<<<2240, 256, 0, stream>>>(ids, emb, X);
    hinit_k<<<256, 256, 0, stream>>>(hidden, H0, H1);
    gemm_p0<<<dim3(8, T), 256, 0, stream>>>(X, W0, b0v, P0);

    {
        const float* P0c = P0;
        void* cargs[] = {(void*)&P0c, (void*)&H0, (void*)&H1,
                         (void*)&W0, (void*)&W1, (void*)&b1v};
        hipLaunchCooperativeKernel((const void*)chain_coop, dim3(128), dim3(256),
                                   cargs, 0, stream);
    }

    wconv<<<5000, 256, 0, stream>>>(Wout, Wbf, (V * 512) / 4);
    aconv<<<T, 256, 0, stream>>>(H1, Abf);
    logits_mfma<<<dim3((V + 127) / 128, T), 256, 0, stream>>>(Abf, Wbf, boutv, out);
    hfinal_k<<<256, 256, 0, stream>>>(H0, H1, out);
}

// Round 3
// 2081.710 us; speedup vs baseline: 1.7967x; 1.7967x over previous
//
#include <hip/hip_runtime.h>

// Sizes
#define T 70
#define B 64
#define E 512
#define H 512
#define V 10000
#define TB (T*B)            // 4480
#define SLOT (H*B)          // 32768 floats per (t) state slot
#define LOGITS_N (T*B*V)    // 44800000
#define NBLK 128            // blocks per layer in chain_flow

typedef __bf16 bf16x8 __attribute__((ext_vector_type(8)));
typedef __bf16 bf16x4 __attribute__((ext_vector_type(4)));
typedef float  f32x4  __attribute__((ext_vector_type(4)));

__device__ __forceinline__ float ftanh(float x) {
    float e = __expf(2.0f * x);
    return 1.0f - 2.0f / (e + 1.0f);
}

// ---------------------------------------------------------------------------
// 1) Embedding gather: X[t][b][e] (row-major) = emb_table[ids[t][b]][e]
// ---------------------------------------------------------------------------
__global__ __launch_bounds__(256) void gather_emb(const int* __restrict__ ids,
                                                  const float* __restrict__ emb,
                                                  float* __restrict__ X) {
    int i = blockIdx.x * 256 + threadIdx.x;
    if (i >= TB * (E / 4)) return;
    int tok = i >> 7;
    int e4 = i & 127;
    int id = ids[tok];
    ((float4*)X)[i] = ((const float4*)emb)[id * 128 + e4];
}

// ---------------------------------------------------------------------------
// 2) Transpose initial hidden -> k4-packed slot 0, and zero the dataflow flags
//    (runs AFTER gemm_p0, right before chain_flow)
// ---------------------------------------------------------------------------
__global__ __launch_bounds__(256) void hinit_k(const float* __restrict__ hidden,
                                               float* __restrict__ H0,
                                               float* __restrict__ H1,
                                               int* __restrict__ FL) {
    int i = blockIdx.x * 256 + threadIdx.x;
    if (i < 2 * T) FL[i] = 0;
    if (i >= 2 * SLOT) return;
    int l = i >> 15, r = i & (SLOT - 1);
    int k4 = r >> 8, q = r & 255, b = q >> 2, kk = q & 3;
    int h = k4 * 4 + kk;
    float v = hidden[l * SLOT + b * H + h];
    (l ? H1 : H0)[r] = v;
}

// ---------------------------------------------------------------------------
// 3) P0 = X @ W0x.T + b0   -> layout (T, N=512, B=64)  (fp32 VALU GEMM)
// ---------------------------------------------------------------------------
__global__ __launch_bounds__(256) void gemm_p0(const float* __restrict__ X,
                                               const float* __restrict__ W0,
                                               const float* __restrict__ b0v,
                                               float* __restrict__ P0) {
    __shared__ float As[32][68];
    __shared__ float Ws[32][68];
    int t = blockIdx.y;
    int n0 = blockIdx.x * 64;
    int tid = threadIdx.x;
    int bq = tid & 15;
    int nq = tid >> 4;
    const float* A = X + t * 64 * E;
    float acc[4][4] = {{0.f}};

    for (int kc = 0; kc < 512; kc += 32) {
        for (int i = tid; i < 512; i += 256) {
            int bb = i >> 3, kq = i & 7;
            float4 a = *(const float4*)(A + bb * E + kc + kq * 4);
            As[kq*4+0][bb] = a.x; As[kq*4+1][bb] = a.y;
            As[kq*4+2][bb] = a.z; As[kq*4+3][bb] = a.w;
        }
        for (int i = tid; i < 512; i += 256) {
            int nn = i >> 3, kq = i & 7;
            float4 w = *(const float4*)(W0 + (size_t)(n0 + nn) * 1024 + kc + kq * 4);
            Ws[kq*4+0][nn] = w.x; Ws[kq*4+1][nn] = w.y;
            Ws[kq*4+2][nn] = w.z; Ws[kq*4+3][nn] = w.w;
        }
        __syncthreads();
#pragma unroll
        for (int kk = 0; kk < 32; kk++) {
            float4 a = *(const float4*)&As[kk][bq * 4];
            float4 w = *(const float4*)&Ws[kk][nq * 4];
            acc[0][0] += a.x*w.x; acc[0][1] += a.x*w.y; acc[0][2] += a.x*w.z; acc[0][3] += a.x*w.w;
            acc[1][0] += a.y*w.x; acc[1][1] += a.y*w.y; acc[1][2] += a.y*w.z; acc[1][3] += a.y*w.w;
            acc[2][0] += a.z*w.x; acc[2][1] += a.z*w.y; acc[2][2] += a.z*w.z; acc[2][3] += a.z*w.w;
            acc[3][0] += a.w*w.x; acc[3][1] += a.w*w.y; acc[3][2] += a.w*w.z; acc[3][3] += a.w*w.w;
        }
        __syncthreads();
    }
#pragma unroll
    for (int j = 0; j < 4; j++) {
        int n = n0 + nq * 4 + j;
        float bias = b0v[n];
        float4 r = make_float4(acc[0][j] + bias, acc[1][j] + bias,
                               acc[2][j] + bias, acc[3][j] + bias);
        *(float4*)(P0 + (size_t)t * SLOT + n * 64 + bq * 4) = r;
    }
}

// ---------------------------------------------------------------------------
// 4) Persistent dataflow chain. 256 blocks (cooperative for co-residency):
//    blocks [0,128): layer0, rows bid*4..+4; blocks [128,256): layer1.
//    Per-step producer counters F0[s], F1[t]; release fetch_add / relaxed spin
//    + acquire fence (no grid barrier). Waves split K (wave w: k4 in
//    [w*32,w*32+32)); LDS reduce across waves. Slots k4-packed.
// ---------------------------------------------------------------------------
__device__ __forceinline__ void spin2(int* fa, int ta, int* fb, int tb) {
    if (threadIdx.x == 0) {
        if (fa)
            while (__hip_atomic_load(fa, __ATOMIC_RELAXED, __HIP_MEMORY_SCOPE_AGENT) < ta)
                __builtin_amdgcn_s_sleep(1);
        if (fb)
            while (__hip_atomic_load(fb, __ATOMIC_RELAXED, __HIP_MEMORY_SCOPE_AGENT) < tb)
                __builtin_amdgcn_s_sleep(1);
        __builtin_amdgcn_fence(__ATOMIC_ACQUIRE, "agent");
    }
    __syncthreads();
}

__device__ __forceinline__ void publish(int* f) {
    // callers: all block stores already drained to L2 by the preceding
    // __syncthreads(); release fence writes back L2 so other XCDs see them.
    if (threadIdx.x == 0) {
        __builtin_amdgcn_fence(__ATOMIC_RELEASE, "agent");
        __hip_atomic_fetch_add(f, 1, __ATOMIC_RELAXED, __HIP_MEMORY_SCOPE_AGENT);
    }
}

__global__ __launch_bounds__(256) void chain_flow(const float* __restrict__ P0,
                                                  float* __restrict__ H0,
                                                  float* __restrict__ H1,
                                                  const float* __restrict__ W0,
                                                  const float* __restrict__ W1,
                                                  const float* __restrict__ b1v,
                                                  int* __restrict__ F0,
                                                  int* __restrict__ F1) {
    __shared__ float red[4][4][64];   // [wave][row][b]
    int tid = threadIdx.x;
    int b = tid & 63;
    int w = __builtin_amdgcn_readfirstlane(tid >> 6);
    int bid = blockIdx.x;

    if (bid < NBLK) {
        // ---- layer 0: h0[s] = tanh(P0[s] + W0h @ h0[s-1]) ----
        int n0 = bid * 4;
        const float* wp = W0 + (size_t)n0 * 1024 + 512 + w * 128;
        for (int s = 0; s < T; s++) {
            spin2(s > 0 ? (F0 + s - 1) : nullptr, NBLK, nullptr, 0);
            const float4* A = (const float4*)(H0 + (size_t)s * SLOT);
            float a0 = 0.f, a1 = 0.f, a2 = 0.f, a3 = 0.f;
#pragma unroll 4
            for (int k = 0; k < 32; k++) {
                float4 a = A[(w * 32 + k) * 64 + b];
                float4 q0 = *(const float4*)(wp + 0 * 1024 + k * 4);
                float4 q1 = *(const float4*)(wp + 1 * 1024 + k * 4);
                float4 q2 = *(const float4*)(wp + 2 * 1024 + k * 4);
                float4 q3 = *(const float4*)(wp + 3 * 1024 + k * 4);
                a0 += a.x*q0.x + a.y*q0.y + a.z*q0.z + a.w*q0.w;
                a1 += a.x*q1.x + a.y*q1.y + a.z*q1.z + a.w*q1.w;
                a2 += a.x*q2.x + a.y*q2.y + a.z*q2.z + a.w*q2.w;
                a3 += a.x*q3.x + a.y*q3.y + a.z*q3.z + a.w*q3.w;
            }
            red[w][0][b] = a0; red[w][1][b] = a1; red[w][2][b] = a2; red[w][3][b] = a3;
            __syncthreads();
            float v = red[0][w][b] + red[1][w][b] + red[2][w][b] + red[3][w][b]
                    + P0[(size_t)s * SLOT + (n0 + w) * 64 + b];
            H0[(size_t)(s + 1) * SLOT + (n0 >> 2) * 256 + b * 4 + w] = ftanh(v);
            __syncthreads();          // drain stores + protect red[] reuse
            publish(F0 + s);
        }
    } else {
        // ---- layer 1: h1[t] = tanh(b1 + W1x @ h0[t] + W1h @ h1[t-1]) ----
        int n0 = (bid - NBLK) * 4;
        const float* wa = W1 + (size_t)n0 * 1024 + w * 128;        // x-part
        const float* wc = W1 + (size_t)n0 * 1024 + 512 + w * 128;  // h-part
        for (int t = 0; t < T; t++) {
            spin2(F0 + t, NBLK, t > 0 ? (F1 + t - 1) : nullptr, NBLK);
            const float4* Aa = (const float4*)(H0 + (size_t)(t + 1) * SLOT);
            const float4* Ac = (const float4*)(H1 + (size_t)t * SLOT);
            float a0 = 0.f, a1 = 0.f, a2 = 0.f, a3 = 0.f;
#pragma unroll 2
            for (int k = 0; k < 32; k++) {
                float4 a = Aa[(w * 32 + k) * 64 + b];
                float4 c = Ac[(w * 32 + k) * 64 + b];
                float4 q0 = *(const float4*)(wa + 0 * 1024 + k * 4);
                float4 q1 = *(const float4*)(wa + 1 * 1024 + k * 4);
                float4 q2 = *(const float4*)(wa + 2 * 1024 + k * 4);
                float4 q3 = *(const float4*)(wa + 3 * 1024 + k * 4);
                float4 p0 = *(const float4*)(wc + 0 * 1024 + k * 4);
                float4 p1 = *(const float4*)(wc + 1 * 1024 + k * 4);
                float4 p2 = *(const float4*)(wc + 2 * 1024 + k * 4);
                float4 p3 = *(const float4*)(wc + 3 * 1024 + k * 4);
                a0 += a.x*q0.x + a.y*q0.y + a.z*q0.z + a.w*q0.w;
                a1 += a.x*q1.x + a.y*q1.y + a.z*q1.z + a.w*q1.w;
                a2 += a.x*q2.x + a.y*q2.y + a.z*q2.z + a.w*q2.w;
                a3 += a.x*q3.x + a.y*q3.y + a.z*q3.z + a.w*q3.w;
                a0 += c.x*p0.x + c.y*p0.y + c.z*p0.z + c.w*p0.w;
                a1 += c.x*p1.x + c.y*p1.y + c.z*p1.z + c.w*p1.w;
                a2 += c.x*p2.x + c.y*p2.y + c.z*p2.z + c.w*p2.w;
                a3 += c.x*p3.x + c.y*p3.y + c.z*p3.z + c.w*p3.w;
            }
            red[w][0][b] = a0; red[w][1][b] = a1; red[w][2][b] = a2; red[w][3][b] = a3;
            __syncthreads();
            float v = red[0][w][b] + red[1][w][b] + red[2][w][b] + red[3][w][b]
                    + b1v[n0 + w];
            H1[(size_t)(t + 1) * SLOT + (n0 >> 2) * 256 + b * 4 + w] = ftanh(v);
            __syncthreads();
            publish(F1 + t);
        }
    }
}

// ---------------------------------------------------------------------------
// 5a) Wout fp32 -> bf16
// ---------------------------------------------------------------------------
__global__ __launch_bounds__(256) void wconv(const float* __restrict__ W,
                                             __bf16* __restrict__ Wb, int n4) {
    int i = blockIdx.x * 256 + threadIdx.x;
    if (i >= n4) return;
    float4 w = ((const float4*)W)[i];
    *(bf16x4*)(Wb + (size_t)i * 4) = (bf16x4){(__bf16)w.x, (__bf16)w.y, (__bf16)w.z, (__bf16)w.w};
}

// ---------------------------------------------------------------------------
// 5b) H1 slots (k4-packed fp32) -> A bf16 row-major (4480, 512)
// ---------------------------------------------------------------------------
__global__ __launch_bounds__(256) void aconv(const float* __restrict__ H1,
                                             __bf16* __restrict__ Abf) {
    int t = blockIdx.x;
    const float4* src = (const float4*)(H1 + (size_t)(t + 1) * SLOT);
    for (int i = threadIdx.x; i < 8192; i += 256) {
        int b = i >> 7, k4 = i & 127;
        float4 a = src[k4 * 64 + b];
        __bf16* dst = Abf + ((size_t)t * 64 + b) * 512 + k4 * 4;
        *(bf16x4*)dst = (bf16x4){(__bf16)a.x, (__bf16)a.y, (__bf16)a.z, (__bf16)a.w};
    }
}

// ---------------------------------------------------------------------------
// 6) logits = tanh(A @ Wout.T + bout) via bf16 MFMA, fp32 accumulate.
// ---------------------------------------------------------------------------
__global__ __launch_bounds__(256) void logits_mfma(const __bf16* __restrict__ A,
                                                   const __bf16* __restrict__ Wb,
                                                   const float* __restrict__ boutv,
                                                   float* __restrict__ out) {
    __shared__ __bf16 As[64 * 64];
    __shared__ __bf16 Bs[128 * 64];
    int t = blockIdx.y;
    int v0 = blockIdx.x * 128;
    int tid = threadIdx.x;
    int lane = tid & 63;
    int w = tid >> 6;
    int l15 = lane & 15;
    int q = lane >> 4;

    f32x4 acc[4][2] = {};
    const __bf16* Ap = A + (size_t)t * 64 * 512;

    for (int kc = 0; kc < 512; kc += 64) {
#pragma unroll
        for (int it = 0; it < 2; it++) {
            int cl = tid + it * 256;
            int m = cl >> 3, c = cl & 7;
            bf16x8 v = *(const bf16x8*)(Ap + m * 512 + kc + c * 8);
            *(bf16x8*)(&As[m * 64 + ((c ^ (m & 7)) * 8)]) = v;
        }
#pragma unroll
        for (int it = 0; it < 4; it++) {
            int cl = tid + it * 256;
            int n = cl >> 3, c = cl & 7;
            int vv = v0 + n;
            bf16x8 val = {};
            if (vv < V) val = *(const bf16x8*)(Wb + (size_t)vv * 512 + kc + c * 8);
            *(bf16x8*)(&Bs[n * 64 + ((c ^ (n & 7)) * 8)]) = val;
        }
        __syncthreads();
#pragma unroll
        for (int s = 0; s < 2; s++) {
            int c = s * 4 + q;
            bf16x8 af[4], bfv[2];
#pragma unroll
            for (int mt = 0; mt < 4; mt++) {
                int m = mt * 16 + l15;
                af[mt] = *(const bf16x8*)(&As[m * 64 + ((c ^ (m & 7)) * 8)]);
            }
#pragma unroll
            for (int nt = 0; nt < 2; nt++) {
                int n = w * 32 + nt * 16 + l15;
                bfv[nt] = *(const bf16x8*)(&Bs[n * 64 + ((c ^ (n & 7)) * 8)]);
            }
#pragma unroll
            for (int mt = 0; mt < 4; mt++)
#pragma unroll
                for (int nt = 0; nt < 2; nt++)
                    acc[mt][nt] = __builtin_amdgcn_mfma_f32_16x16x32_bf16(af[mt], bfv[nt], acc[mt][nt], 0, 0, 0);
        }
        __syncthreads();
    }

#pragma unroll
    for (int nt = 0; nt < 2; nt++) {
        int col = v0 + w * 32 + nt * 16 + l15;
        if (col < V) {
            float bias = boutv[col];
#pragma unroll
            for (int mt = 0; mt < 4; mt++) {
#pragma unroll
                for (int r = 0; r < 4; r++) {
                    int row = mt * 16 + q * 4 + r;
                    out[((size_t)t * 64 + row) * V + col] = ftanh(acc[mt][nt][r] + bias);
                }
            }
        }
    }
}

// ---------------------------------------------------------------------------
// 7) Final hidden -> d_out tail, (L,B,H) row-major
// ---------------------------------------------------------------------------
__global__ __launch_bounds__(256) void hfinal_k(const float* __restrict__ H0,
                                                const float* __restrict__ H1,
                                                float* __restrict__ out) {
    int i = blockIdx.x * 256 + threadIdx.x;
    if (i >= 2 * SLOT) return;
    int l = i >> 15, r = i & (SLOT - 1);
    int b = r >> 9, h = r & 511;
    const float* Hp = l ? H1 : H0;
    out[LOGITS_N + i] = Hp[(size_t)T * SLOT + (h >> 2) * 256 + b * 4 + (h & 3)];
}

// ---------------------------------------------------------------------------
extern "C" void kernel_launch(void* const* d_in, const int* in_sizes, int n_in,
                              void* d_out, int out_size, void* d_ws, size_t ws_size,
                              hipStream_t stream) {
    const int*   ids    = (const int*)d_in[0];
    const float* hidden = (const float*)d_in[1];
    const float* emb    = (const float*)d_in[2];
    const float* W0     = (const float*)d_in[3];
    const float* b0v    = (const float*)d_in[4];
    const float* W1     = (const float*)d_in[5];
    const float* b1v    = (const float*)d_in[6];
    const float* Wout   = (const float*)d_in[7];
    const float* boutv  = (const float*)d_in[8];
    float* out = (float*)d_out;
    float* ws  = (float*)d_ws;

    // ws layout (floats): [H0: 2,326,528][H1: 2,326,528][P0: 2,293,760][X: 2,293,760]
    // Wbf16 aliases P0 (+266,240-float spill into X head, dead after gemm_p0);
    // Abf16 aliases X at +266,240; flags live in X tail past Abf (zeroed by
    // hinit_k AFTER gemm_p0 has consumed X). Total 9,240,576 floats.
    float* H0 = ws;
    float* H1 = ws + 2326528;
    float* P0 = ws + 4653056;
    float* X  = ws + 6946816;
    __bf16* Wbf = (__bf16*)(ws + 4653056);            // 5,120,000 bf16
    __bf16* Abf = (__bf16*)(ws + 6946816 + 266240);   // 2,293,760 bf16
    int* FL = (int*)(ws + 9240416);                   // 140 ints, inside X tail
    int* F0 = FL;
    int* F1 = FL + T;

    gather_emb<<<2240, 256, 0, stream>>>(ids, emb, X);
    gemm_p0<<<dim3(8, T), 256, 0, stream>>>(X, W0, b0v, P0);
    hinit_k<<<256, 256, 0, stream>>>(hidden, H0, H1, FL);

    {
        const float* P0c = P0;
        void* cargs[] = {(void*)&P0c, (void*)&H0, (void*)&H1,
                         (void*)&W0, (void*)&W1, (void*)&b1v,
                         (void*)&F0, (void*)&F1};
        hipLaunchCooperativeKernel((const void*)chain_flow, dim3(256), dim3(256),
                                   cargs, 0, stream);
    }

    wconv<<<5000, 256, 0, stream>>>(Wout, Wbf, (V * 512) / 4);
    aconv<<<T, 256, 0, stream>>>(H1, Abf);
    logits_mfma<<<dim3((V + 127) / 128, T), 256, 0, stream>>>(Abf, Wbf, boutv, out);
    hfinal_k<<<256, 256, 0, stream>>>(H0, H1, out);
}